// Round 1
// baseline (1448.530 us; speedup 1.0000x reference)
//
#include <hip/hip_runtime.h>
#include <stdint.h>

// Problem constants (fixed by setup_inputs in the reference)
#define BB 32
#define PP 24564
#define CC 81
#define OO 32

__device__ __constant__ const float V0 = 0.1f;
__device__ __constant__ const float V1 = 0.2f;

// ---------------- workspace layout (bytes) ----------------
// bt_idx : int   [B*P]   @ 0
// bt_ov  : float [B*P]   @ 3,144,192
// lc     : float [B*P]   @ 6,288,384
// bp_key : u64   [B*O]   @ 9,432,576
// num_pos: int   [B]     @ 9,440,768
// scalars: float [2]     @ 9,440,896   (0: loss_l sum, 1: loss_c sum)

__global__ void k_init(unsigned long long* bp_key, int* num_pos, float* scalars) {
    int i = blockIdx.x * blockDim.x + threadIdx.x;
    if (i < BB * OO) bp_key[i] = 0ULL;
    if (i < BB) num_pos[i] = 0;
    if (i < 2) scalars[i] = 0.0f;
}

// One thread per (b, prior). Computes best-truth per prior and contributes to
// best-prior-per-truth via packed-key atomicMax (first-index tie-break via ~p).
__global__ __launch_bounds__(256) void k_match(const float4* __restrict__ priors,
                                               const float4* __restrict__ boxes,
                                               float* __restrict__ bt_ov,
                                               int* __restrict__ bt_idx,
                                               unsigned long long* __restrict__ bp_key) {
    int b = blockIdx.y;
    int p = blockIdx.x * 256 + threadIdx.x;

    __shared__ float4 s_box[OO];
    __shared__ float s_area[OO];
    __shared__ unsigned long long s_key[OO];

    if (threadIdx.x < OO) {
        float4 t = boxes[b * OO + threadIdx.x];
        s_box[threadIdx.x] = t;
        s_area[threadIdx.x] = (t.z - t.x) * (t.w - t.y);
        s_key[threadIdx.x] = 0ULL;
    }
    __syncthreads();

    if (p < PP) {
        float4 pr = priors[p];  // center form cx,cy,w,h
        float ax0 = pr.x - pr.z * 0.5f;
        float ay0 = pr.y - pr.w * 0.5f;
        float ax1 = pr.x + pr.z * 0.5f;
        float ay1 = pr.y + pr.w * 0.5f;
        float area_a = (ax1 - ax0) * (ay1 - ay0);

        float best = -1.0f;
        int bidx = 0;
        unsigned int pk = 0xFFFFFFFFu - (unsigned int)p;  // smaller p -> larger key

        #pragma unroll 8
        for (int o = 0; o < OO; ++o) {
            float4 t = s_box[o];
            float lx = fmaxf(ax0, t.x), ly = fmaxf(ay0, t.y);
            float rx = fminf(ax1, t.z), ry = fminf(ay1, t.w);
            float w = fmaxf(rx - lx, 0.0f), h = fmaxf(ry - ly, 0.0f);
            float inter = w * h;
            float iou = inter / (area_a + s_area[o] - inter);
            if (iou > best) { best = iou; bidx = o; }  // first-max wins (strict >)
            unsigned long long key =
                ((unsigned long long)__float_as_uint(iou) << 32) | (unsigned long long)pk;
            atomicMax(&s_key[o], key);
        }
        bt_ov[b * PP + p] = best;
        bt_idx[b * PP + p] = bidx;
    }
    __syncthreads();
    if (threadIdx.x < OO) atomicMax(&bp_key[b * OO + threadIdx.x], s_key[threadIdx.x]);
}

// Serial per batch: force each truth's best prior; later truths win on duplicates.
__global__ void k_scatter(const unsigned long long* __restrict__ bp_key,
                          float* __restrict__ bt_ov, int* __restrict__ bt_idx) {
    int b = blockIdx.x * blockDim.x + threadIdx.x;
    if (b < BB) {
        for (int o = 0; o < OO; ++o) {
            unsigned long long key = bp_key[b * OO + o];
            unsigned int p = 0xFFFFFFFFu - (unsigned int)(key & 0xFFFFFFFFull);
            bt_idx[b * PP + p] = o;
            bt_ov[b * PP + p] = 2.0f;
        }
    }
}

// 16 lanes per (b,p) row: log-softmax CE, positive bookkeeping, loc loss.
__global__ __launch_bounds__(256) void k_ce(const float* __restrict__ conf,
                                            const float* __restrict__ loc_preds,
                                            const float4* __restrict__ priors,
                                            const float4* __restrict__ boxes,
                                            const int* __restrict__ labels,
                                            const float* __restrict__ bt_ov,
                                            const int* __restrict__ bt_idx,
                                            float* __restrict__ lc,
                                            int* __restrict__ num_pos,
                                            float* __restrict__ scalars) {
    int r = blockIdx.x * 16 + (threadIdx.x >> 4);
    int lane = threadIdx.x & 15;
    if (r >= BB * PP) return;
    int b = r / PP;
    int p = r - b * PP;

    const float* row = conf + (size_t)r * CC;
    float x[6];
    #pragma unroll
    for (int s = 0; s < 6; ++s) {
        int idx = lane + 16 * s;
        x[s] = (idx < CC) ? row[idx] : -INFINITY;
    }

    // max over 81 classes (16-lane group reduce)
    float m = fmaxf(fmaxf(fmaxf(x[0], x[1]), fmaxf(x[2], x[3])), fmaxf(x[4], x[5]));
    #pragma unroll
    for (int off = 1; off < 16; off <<= 1) m = fmaxf(m, __shfl_xor(m, off, 16));

    float sum = 0.0f;
    #pragma unroll
    for (int s = 0; s < 6; ++s) sum += __expf(x[s] - m);
    #pragma unroll
    for (int off = 1; off < 16; off <<= 1) sum += __shfl_xor(sum, off, 16);
    float lse = __logf(sum) + m;

    int cls = 0;
    int t = 0;
    if (lane == 0) {
        t = bt_idx[r];
        float ov = bt_ov[r];
        cls = labels[b * OO + t];
        if (ov < 0.5f) cls = 0;
    }
    cls = __shfl(cls, 0, 16);

    // fetch x[cls] without dynamic register indexing
    int slot = cls >> 4;
    float xs = x[0];
    #pragma unroll
    for (int s = 1; s < 6; ++s) xs = (slot == s) ? x[s] : xs;
    float xt = __shfl(xs, cls & 15, 16);
    float ce = lse - xt;

    if (lane == 0) {
        bool pos = cls > 0;
        lc[r] = pos ? 0.0f : ce;
        if (pos) {
            atomicAdd(&num_pos[b], 1);
            atomicAdd(&scalars[1], ce);
            // encode(truths[t], priors[p]) and smooth-L1 against loc_preds
            float4 tb = boxes[b * OO + t];  // corner form
            float4 pr = priors[p];          // center form
            float gx = ((tb.x + tb.z) * 0.5f - pr.x) / (V0 * pr.z);
            float gy = ((tb.y + tb.w) * 0.5f - pr.y) / (V0 * pr.w);
            float gw = logf((tb.z - tb.x) / pr.z) / V1;
            float gh = logf((tb.w - tb.y) / pr.w) / V1;
            const float* lp = loc_preds + (size_t)r * 4;
            float d0 = fabsf(lp[0] - gx);
            float d1 = fabsf(lp[1] - gy);
            float d2 = fabsf(lp[2] - gw);
            float d3 = fabsf(lp[3] - gh);
            float s = 0.0f;
            s += (d0 < 1.0f) ? 0.5f * d0 * d0 : d0 - 0.5f;
            s += (d1 < 1.0f) ? 0.5f * d1 * d1 : d1 - 0.5f;
            s += (d2 < 1.0f) ? 0.5f * d2 * d2 : d2 - 0.5f;
            s += (d3 < 1.0f) ? 0.5f * d3 * d3 : d3 - 0.5f;
            atomicAdd(&scalars[0], s);
        }
    }
}

// One block per batch: exact top-k sum of lc via 31-bit MSB radix select.
// k-th-largest ties contribute identically, so (sum > v) + (k - cnt_gt)*v is exact.
__global__ __launch_bounds__(1024) void k_select(const float* __restrict__ lc,
                                                 const int* __restrict__ num_pos,
                                                 float* __restrict__ scalars) {
    int b = blockIdx.x;
    const float* v = lc + (size_t)b * PP;
    int np = num_pos[b];
    long long k0 = 3LL * (long long)np;
    int k = (k0 < (long long)(PP - 1)) ? (int)k0 : (PP - 1);

    __shared__ int s_cnt[16];
    __shared__ float s_sum[16];
    __shared__ unsigned int s_prefix;
    __shared__ int s_k;

    // register-resident values; pad with 0 (harmless for top-k of nonneg floats)
    unsigned int val[24];
    #pragma unroll
    for (int i = 0; i < 24; ++i) {
        int idx = threadIdx.x + i * 1024;
        val[i] = (idx < PP) ? __float_as_uint(v[idx]) : 0u;
    }

    if (k <= 0) return;  // uniform per block

    if (threadIdx.x == 0) { s_prefix = 0u; s_k = k; }
    __syncthreads();

    unsigned int prefix = 0u;
    for (int bit = 30; bit >= 0; --bit) {
        unsigned int cand = prefix | (1u << bit);
        unsigned int hi = cand >> bit;
        int c = 0;
        #pragma unroll
        for (int i = 0; i < 24; ++i) c += ((val[i] >> bit) == hi);
        #pragma unroll
        for (int off = 32; off; off >>= 1) c += __shfl_down(c, off, 64);
        int wid = threadIdx.x >> 6;
        if ((threadIdx.x & 63) == 0) s_cnt[wid] = c;
        __syncthreads();
        if (threadIdx.x == 0) {
            int tot = 0;
            #pragma unroll
            for (int i = 0; i < 16; ++i) tot += s_cnt[i];
            if (tot >= s_k) s_prefix = cand; else s_k -= tot;
        }
        __syncthreads();
        prefix = s_prefix;
    }

    // sum of elements strictly greater than v_thresh, plus remaining ties
    float fv = __uint_as_float(prefix);
    float ssum = 0.0f;
    int cgt = 0;
    #pragma unroll
    for (int i = 0; i < 24; ++i) {
        if (val[i] > prefix) { ssum += __uint_as_float(val[i]); cgt++; }
    }
    #pragma unroll
    for (int off = 32; off; off >>= 1) {
        ssum += __shfl_down(ssum, off, 64);
        cgt += __shfl_down(cgt, off, 64);
    }
    int wid = threadIdx.x >> 6;
    if ((threadIdx.x & 63) == 0) { s_cnt[wid] = cgt; s_sum[wid] = ssum; }
    __syncthreads();
    if (threadIdx.x == 0) {
        int ct = 0;
        float st = 0.0f;
        #pragma unroll
        for (int i = 0; i < 16; ++i) { ct += s_cnt[i]; st += s_sum[i]; }
        float topk = st + (float)(k - ct) * fv;
        atomicAdd(&scalars[1], topk);
    }
}

__global__ void k_final(const int* __restrict__ num_pos,
                        const float* __restrict__ scalars,
                        float* __restrict__ out) {
    if (threadIdx.x == 0 && blockIdx.x == 0) {
        int N = 0;
        for (int b = 0; b < BB; ++b) N += num_pos[b];
        float fN = (float)N;
        out[0] = scalars[0] / fN + scalars[1] / fN;
    }
}

extern "C" void kernel_launch(void* const* d_in, const int* in_sizes, int n_in,
                              void* d_out, int out_size, void* d_ws, size_t ws_size,
                              hipStream_t stream) {
    const float* loc_preds = (const float*)d_in[0];   // [B,P,4]
    const float* conf_preds = (const float*)d_in[1];  // [B,P,C]
    const float* priors = (const float*)d_in[2];      // [P,4] center form
    const float* boxes = (const float*)d_in[3];       // [B,O,4] corner form
    const int* labels = (const int*)d_in[4];          // [B,O]

    char* ws = (char*)d_ws;
    const size_t SZ_BP = (size_t)BB * PP;
    int* bt_idx = (int*)(ws);
    float* bt_ov = (float*)(ws + SZ_BP * 4);
    float* lc = (float*)(ws + SZ_BP * 8);
    unsigned long long* bp_key = (unsigned long long*)(ws + SZ_BP * 12);
    int* num_pos = (int*)(ws + SZ_BP * 12 + (size_t)BB * OO * 8);
    float* scalars = (float*)(ws + SZ_BP * 12 + (size_t)BB * OO * 8 + 128);

    k_init<<<4, 256, 0, stream>>>(bp_key, num_pos, scalars);

    dim3 g1((PP + 255) / 256, BB);
    k_match<<<g1, 256, 0, stream>>>((const float4*)priors, (const float4*)boxes,
                                    bt_ov, bt_idx, bp_key);

    k_scatter<<<1, 64, 0, stream>>>(bp_key, bt_ov, bt_idx);

    int rows = BB * PP;
    k_ce<<<(rows + 15) / 16, 256, 0, stream>>>(conf_preds, loc_preds,
                                               (const float4*)priors, (const float4*)boxes,
                                               labels, bt_ov, bt_idx, lc, num_pos, scalars);

    k_select<<<BB, 1024, 0, stream>>>(lc, num_pos, scalars);

    k_final<<<1, 64, 0, stream>>>(num_pos, scalars, (float*)d_out);
}

// Round 2
// 583.995 us; speedup vs baseline: 2.4804x; 2.4804x over previous
//
#include <hip/hip_runtime.h>
#include <stdint.h>

// Problem constants (fixed by setup_inputs in the reference)
#define BB 32
#define PP 24564
#define CC 81
#define OO 32

#define V0c 0.1f
#define V1c 0.2f

// ---------------- workspace layout (bytes) ----------------
// bt_idx  : int   [B*P]  @ 0
// bt_ov   : float [B*P]  @ 3,144,192
// lc      : float [B*P]  @ 6,288,384
// bp_key  : u64   [B*O]  @ 9,432,576
// ls_slots: float [64]   @ 9,440,768
// cs_slots: float [64]   @ 9,441,024
// num_pos : int   [32]   @ 9,441,280

__global__ void k_init(float* ls_slots, float* cs_slots, int* num_pos) {
    int i = threadIdx.x;
    if (i < 64) { ls_slots[i] = 0.0f; cs_slots[i] = 0.0f; }
    if (i < BB) num_pos[i] = 0;
}

// One thread per (b, prior): best-truth per prior only. No atomics.
__global__ __launch_bounds__(256) void k_match(const float4* __restrict__ priors,
                                               const float4* __restrict__ boxes,
                                               float* __restrict__ bt_ov,
                                               int* __restrict__ bt_idx) {
    int b = blockIdx.y;
    int p = blockIdx.x * 256 + threadIdx.x;

    __shared__ float4 s_box[OO];
    __shared__ float s_area[OO];

    if (threadIdx.x < OO) {
        float4 t = boxes[b * OO + threadIdx.x];
        s_box[threadIdx.x] = t;
        s_area[threadIdx.x] = (t.z - t.x) * (t.w - t.y);
    }
    __syncthreads();

    if (p < PP) {
        float4 pr = priors[p];  // center form
        float ax0 = pr.x - pr.z * 0.5f;
        float ay0 = pr.y - pr.w * 0.5f;
        float ax1 = pr.x + pr.z * 0.5f;
        float ay1 = pr.y + pr.w * 0.5f;
        float area_a = (ax1 - ax0) * (ay1 - ay0);

        float best = -1.0f;
        int bidx = 0;
        #pragma unroll 8
        for (int o = 0; o < OO; ++o) {
            float4 t = s_box[o];
            float lx = fmaxf(ax0, t.x), ly = fmaxf(ay0, t.y);
            float rx = fminf(ax1, t.z), ry = fminf(ay1, t.w);
            float w = fmaxf(rx - lx, 0.0f), h = fmaxf(ry - ly, 0.0f);
            float inter = w * h;
            float iou = inter / (area_a + s_area[o] - inter);
            if (iou > best) { best = iou; bidx = o; }  // first-max wins
        }
        bt_ov[b * PP + p] = best;
        bt_idx[b * PP + p] = bidx;
    }
}

// One block per (b,o): max over all P priors of packed (iou, ~p) key.
// Pure reduction, no atomics. Priors are L2-resident.
__global__ __launch_bounds__(256) void k_bestprior(const float4* __restrict__ priors,
                                                   const float4* __restrict__ boxes,
                                                   unsigned long long* __restrict__ bp_key) {
    int o = blockIdx.x;
    int b = blockIdx.y;
    float4 t = boxes[b * OO + o];
    float area_b = (t.z - t.x) * (t.w - t.y);

    unsigned long long best = 0ULL;
    for (int p = threadIdx.x; p < PP; p += 256) {
        float4 pr = priors[p];
        float ax0 = pr.x - pr.z * 0.5f;
        float ay0 = pr.y - pr.w * 0.5f;
        float ax1 = pr.x + pr.z * 0.5f;
        float ay1 = pr.y + pr.w * 0.5f;
        float area_a = (ax1 - ax0) * (ay1 - ay0);
        float lx = fmaxf(ax0, t.x), ly = fmaxf(ay0, t.y);
        float rx = fminf(ax1, t.z), ry = fminf(ay1, t.w);
        float w = fmaxf(rx - lx, 0.0f), h = fmaxf(ry - ly, 0.0f);
        float inter = w * h;
        float iou = inter / (area_a + area_b - inter);
        unsigned long long key = ((unsigned long long)__float_as_uint(iou) << 32) |
                                 (unsigned long long)(0xFFFFFFFFu - (unsigned int)p);
        best = (key > best) ? key : best;
    }
    // wave reduce (64-bit shuffles)
    #pragma unroll
    for (int off = 32; off; off >>= 1) {
        unsigned long long other = __shfl_down(best, off, 64);
        best = (other > best) ? other : best;
    }
    __shared__ unsigned long long s_w[4];
    int wid = threadIdx.x >> 6;
    if ((threadIdx.x & 63) == 0) s_w[wid] = best;
    __syncthreads();
    if (threadIdx.x == 0) {
        unsigned long long m = s_w[0];
        for (int i = 1; i < 4; ++i) m = (s_w[i] > m) ? s_w[i] : m;
        bp_key[b * OO + o] = m;
    }
}

// Serial per batch: force each truth's best prior; later truths win on duplicates.
__global__ void k_scatter(const unsigned long long* __restrict__ bp_key,
                          float* __restrict__ bt_ov, int* __restrict__ bt_idx) {
    int b = blockIdx.x * blockDim.x + threadIdx.x;
    if (b < BB) {
        for (int o = 0; o < OO; ++o) {
            unsigned long long key = bp_key[b * OO + o];
            unsigned int p = 0xFFFFFFFFu - (unsigned int)(key & 0xFFFFFFFFull);
            bt_idx[b * PP + p] = o;
            bt_ov[b * PP + p] = 2.0f;
        }
    }
}

// 16 lanes per (b,p) row: log-softmax CE, positive bookkeeping, loc loss.
// Per-positive sums reduced per-block, <=4 atomics per block (64-slot scatter).
__global__ __launch_bounds__(256) void k_ce(const float* __restrict__ conf,
                                            const float* __restrict__ loc_preds,
                                            const float4* __restrict__ priors,
                                            const float4* __restrict__ boxes,
                                            const int* __restrict__ labels,
                                            const float* __restrict__ bt_ov,
                                            const int* __restrict__ bt_idx,
                                            float* __restrict__ lc,
                                            int* __restrict__ num_pos,
                                            float* __restrict__ ls_slots,
                                            float* __restrict__ cs_slots) {
    int r = blockIdx.x * 16 + (threadIdx.x >> 4);
    int lane = threadIdx.x & 15;
    int g = threadIdx.x >> 4;
    // grid sized exactly: r < BB*PP always (786048 = 49128*16)
    int b = r / PP;
    int p = r - b * PP;

    const float* row = conf + (size_t)r * CC;
    float x[6];
    #pragma unroll
    for (int s = 0; s < 6; ++s) {
        int idx = lane + 16 * s;
        x[s] = (idx < CC) ? row[idx] : -INFINITY;
    }

    float m = fmaxf(fmaxf(fmaxf(x[0], x[1]), fmaxf(x[2], x[3])), fmaxf(x[4], x[5]));
    #pragma unroll
    for (int off = 1; off < 16; off <<= 1) m = fmaxf(m, __shfl_xor(m, off, 16));

    float sum = 0.0f;
    #pragma unroll
    for (int s = 0; s < 6; ++s) sum += __expf(x[s] - m);
    #pragma unroll
    for (int off = 1; off < 16; off <<= 1) sum += __shfl_xor(sum, off, 16);
    float lse = __logf(sum) + m;

    int cls = 0;
    int t = 0;
    if (lane == 0) {
        t = bt_idx[r];
        float ov = bt_ov[r];
        cls = labels[b * OO + t];
        if (ov < 0.5f) cls = 0;
    }
    cls = __shfl(cls, 0, 16);

    // fetch x[cls] without dynamic register indexing
    int slot = cls >> 4;
    float xs = x[0];
    #pragma unroll
    for (int s = 1; s < 6; ++s) xs = (slot == s) ? x[s] : xs;
    float xt = __shfl(xs, cls & 15, 16);
    float ce = lse - xt;

    __shared__ float red_ce[16];
    __shared__ float red_ls[16];
    __shared__ int red_cnt[16];
    __shared__ int red_b[16];

    if (lane == 0) {
        bool pos = cls > 0;
        lc[r] = pos ? 0.0f : ce;
        float s = 0.0f;
        if (pos) {
            float4 tb = boxes[b * OO + t];  // corner form
            float4 pr = priors[p];          // center form
            float gx = ((tb.x + tb.z) * 0.5f - pr.x) / (V0c * pr.z);
            float gy = ((tb.y + tb.w) * 0.5f - pr.y) / (V0c * pr.w);
            float gw = logf((tb.z - tb.x) / pr.z) / V1c;
            float gh = logf((tb.w - tb.y) / pr.w) / V1c;
            const float* lp = loc_preds + (size_t)r * 4;
            float d0 = fabsf(lp[0] - gx);
            float d1 = fabsf(lp[1] - gy);
            float d2 = fabsf(lp[2] - gw);
            float d3 = fabsf(lp[3] - gh);
            s += (d0 < 1.0f) ? 0.5f * d0 * d0 : d0 - 0.5f;
            s += (d1 < 1.0f) ? 0.5f * d1 * d1 : d1 - 0.5f;
            s += (d2 < 1.0f) ? 0.5f * d2 * d2 : d2 - 0.5f;
            s += (d3 < 1.0f) ? 0.5f * d3 * d3 : d3 - 0.5f;
        }
        red_ce[g] = pos ? ce : 0.0f;
        red_ls[g] = s;
        red_cnt[g] = pos ? 1 : 0;
        red_b[g] = b;
    }
    __syncthreads();
    if (threadIdx.x == 0) {
        float ces = 0.0f, lss = 0.0f;
        int c0 = 0, c1 = 0;
        int b0 = red_b[0];
        #pragma unroll
        for (int i = 0; i < 16; ++i) {
            ces += red_ce[i];
            lss += red_ls[i];
            if (red_b[i] == b0) c0 += red_cnt[i]; else c1 += red_cnt[i];
        }
        if (c0) atomicAdd(&num_pos[b0], c0);
        if (c1) atomicAdd(&num_pos[b0 + 1], c1);
        if (c0 + c1) {
            int sl = blockIdx.x & 63;
            atomicAdd(&ls_slots[sl], lss);
            atomicAdd(&cs_slots[sl], ces);
        }
    }
}

// One block per batch: exact top-k sum of lc via 31-bit MSB radix select.
__global__ __launch_bounds__(1024) void k_select(const float* __restrict__ lc,
                                                 const int* __restrict__ num_pos,
                                                 float* __restrict__ cs_slots) {
    int b = blockIdx.x;
    const float* v = lc + (size_t)b * PP;
    int np = num_pos[b];
    long long k0 = 3LL * (long long)np;
    int k = (k0 < (long long)(PP - 1)) ? (int)k0 : (PP - 1);

    __shared__ int s_cnt[16];
    __shared__ float s_sum[16];
    __shared__ unsigned int s_prefix;
    __shared__ int s_k;

    unsigned int val[24];
    #pragma unroll
    for (int i = 0; i < 24; ++i) {
        int idx = threadIdx.x + i * 1024;
        val[i] = (idx < PP) ? __float_as_uint(v[idx]) : 0u;
    }

    if (k <= 0) return;  // uniform per block

    if (threadIdx.x == 0) { s_prefix = 0u; s_k = k; }
    __syncthreads();

    unsigned int prefix = 0u;
    for (int bit = 30; bit >= 0; --bit) {
        unsigned int cand = prefix | (1u << bit);
        unsigned int hi = cand >> bit;
        int c = 0;
        #pragma unroll
        for (int i = 0; i < 24; ++i) c += ((val[i] >> bit) == hi);
        #pragma unroll
        for (int off = 32; off; off >>= 1) c += __shfl_down(c, off, 64);
        int wid = threadIdx.x >> 6;
        if ((threadIdx.x & 63) == 0) s_cnt[wid] = c;
        __syncthreads();
        if (threadIdx.x == 0) {
            int tot = 0;
            #pragma unroll
            for (int i = 0; i < 16; ++i) tot += s_cnt[i];
            if (tot >= s_k) s_prefix = cand; else s_k -= tot;
        }
        __syncthreads();
        prefix = s_prefix;
    }

    float fv = __uint_as_float(prefix);
    float ssum = 0.0f;
    int cgt = 0;
    #pragma unroll
    for (int i = 0; i < 24; ++i) {
        if (val[i] > prefix) { ssum += __uint_as_float(val[i]); cgt++; }
    }
    #pragma unroll
    for (int off = 32; off; off >>= 1) {
        ssum += __shfl_down(ssum, off, 64);
        cgt += __shfl_down(cgt, off, 64);
    }
    int wid = threadIdx.x >> 6;
    if ((threadIdx.x & 63) == 0) { s_cnt[wid] = cgt; s_sum[wid] = ssum; }
    __syncthreads();
    if (threadIdx.x == 0) {
        int ct = 0;
        float st = 0.0f;
        #pragma unroll
        for (int i = 0; i < 16; ++i) { ct += s_cnt[i]; st += s_sum[i]; }
        float topk = st + (float)(k - ct) * fv;
        atomicAdd(&cs_slots[b], topk);  // b < 32: spread, 1 atomic/block
    }
}

__global__ void k_final(const int* __restrict__ num_pos,
                        const float* __restrict__ ls_slots,
                        const float* __restrict__ cs_slots,
                        float* __restrict__ out) {
    if (threadIdx.x == 0 && blockIdx.x == 0) {
        int N = 0;
        for (int b = 0; b < BB; ++b) N += num_pos[b];
        float Sl = 0.0f, Sc = 0.0f;
        for (int i = 0; i < 64; ++i) { Sl += ls_slots[i]; Sc += cs_slots[i]; }
        float fN = (float)N;
        out[0] = Sl / fN + Sc / fN;
    }
}

extern "C" void kernel_launch(void* const* d_in, const int* in_sizes, int n_in,
                              void* d_out, int out_size, void* d_ws, size_t ws_size,
                              hipStream_t stream) {
    const float* loc_preds = (const float*)d_in[0];   // [B,P,4]
    const float* conf_preds = (const float*)d_in[1];  // [B,P,C]
    const float* priors = (const float*)d_in[2];      // [P,4] center form
    const float* boxes = (const float*)d_in[3];       // [B,O,4] corner form
    const int* labels = (const int*)d_in[4];          // [B,O]

    char* ws = (char*)d_ws;
    const size_t SZ_BP = (size_t)BB * PP;
    int* bt_idx = (int*)(ws);
    float* bt_ov = (float*)(ws + SZ_BP * 4);
    float* lc = (float*)(ws + SZ_BP * 8);
    unsigned long long* bp_key = (unsigned long long*)(ws + SZ_BP * 12);
    float* ls_slots = (float*)(ws + SZ_BP * 12 + (size_t)BB * OO * 8);
    float* cs_slots = ls_slots + 64;
    int* num_pos = (int*)(cs_slots + 64);

    k_init<<<1, 256, 0, stream>>>(ls_slots, cs_slots, num_pos);

    dim3 g1((PP + 255) / 256, BB);
    k_match<<<g1, 256, 0, stream>>>((const float4*)priors, (const float4*)boxes,
                                    bt_ov, bt_idx);

    dim3 g2(OO, BB);
    k_bestprior<<<g2, 256, 0, stream>>>((const float4*)priors, (const float4*)boxes,
                                        bp_key);

    k_scatter<<<1, 64, 0, stream>>>(bp_key, bt_ov, bt_idx);

    int rows = BB * PP;
    k_ce<<<(rows + 15) / 16, 256, 0, stream>>>(conf_preds, loc_preds,
                                               (const float4*)priors, (const float4*)boxes,
                                               labels, bt_ov, bt_idx, lc, num_pos,
                                               ls_slots, cs_slots);

    k_select<<<BB, 1024, 0, stream>>>(lc, num_pos, cs_slots);

    k_final<<<1, 64, 0, stream>>>(num_pos, ls_slots, cs_slots, (float*)d_out);
}

// Round 3
// 574.297 us; speedup vs baseline: 2.5223x; 1.0169x over previous
//
#include <hip/hip_runtime.h>
#include <stdint.h>

// Problem constants (fixed by setup_inputs in the reference)
#define BB 32
#define PP 24564
#define CC 81
#define OO 32

#define V0c 0.1f
#define V1c 0.2f

#define ROWS 64                 // rows per k_ce block
#define CHUNK (ROWS * CC)       // 5184 floats, 16B-aligned chunk per block
#define CHUNK4 (CHUNK / 4)      // 1296 float4

// ---------------- workspace layout ----------------
// bt_idx  : int   [B*P]
// bt_ov   : float [B*P]
// lc      : float [B*P]
// bp_key  : u64   [B*O]
// ls_slots: float [64]
// cs_slots: float [64]
// num_pos : int   [32]

__global__ void k_init(unsigned long long* bp_key, float* ls_slots, float* cs_slots,
                       int* num_pos) {
    int i = blockIdx.x * 256 + threadIdx.x;
    if (i < BB * OO) bp_key[i] = 0ULL;
    if (i < 64) { ls_slots[i] = 0.0f; cs_slots[i] = 0.0f; }
    if (i < BB) num_pos[i] = 0;
}

// One thread per (b, prior): best-truth per prior only. No atomics.
__global__ __launch_bounds__(256) void k_match(const float4* __restrict__ priors,
                                               const float4* __restrict__ boxes,
                                               float* __restrict__ bt_ov,
                                               int* __restrict__ bt_idx) {
    int b = blockIdx.y;
    int p = blockIdx.x * 256 + threadIdx.x;

    __shared__ float4 s_box[OO];
    __shared__ float s_area[OO];

    if (threadIdx.x < OO) {
        float4 t = boxes[b * OO + threadIdx.x];
        s_box[threadIdx.x] = t;
        s_area[threadIdx.x] = (t.z - t.x) * (t.w - t.y);
    }
    __syncthreads();

    if (p < PP) {
        float4 pr = priors[p];  // center form
        float ax0 = pr.x - pr.z * 0.5f;
        float ay0 = pr.y - pr.w * 0.5f;
        float ax1 = pr.x + pr.z * 0.5f;
        float ay1 = pr.y + pr.w * 0.5f;
        float area_a = (ax1 - ax0) * (ay1 - ay0);

        float best = -1.0f;
        int bidx = 0;
        #pragma unroll 8
        for (int o = 0; o < OO; ++o) {
            float4 t = s_box[o];
            float lx = fmaxf(ax0, t.x), ly = fmaxf(ay0, t.y);
            float rx = fminf(ax1, t.z), ry = fminf(ay1, t.w);
            float w = fmaxf(rx - lx, 0.0f), h = fmaxf(ry - ly, 0.0f);
            float inter = w * h;
            float iou = inter / (area_a + s_area[o] - inter);
            if (iou > best) { best = iou; bidx = o; }  // first-max wins
        }
        bt_ov[b * PP + p] = best;
        bt_idx[b * PP + p] = bidx;
    }
}

// Grid (O, B, 8): each block scans 1/8 of priors for one (b,o); global atomicMax
// on packed (iou, ~p) key merges segments. 8 atomics per address total.
__global__ __launch_bounds__(256) void k_bestprior(const float4* __restrict__ priors,
                                                   const float4* __restrict__ boxes,
                                                   unsigned long long* __restrict__ bp_key) {
    int o = blockIdx.x;
    int b = blockIdx.y;
    const int NSEG = 8;
    const int SEG = (PP + NSEG - 1) / NSEG;
    int p0 = blockIdx.z * SEG;
    int p1 = p0 + SEG;
    if (p1 > PP) p1 = PP;

    float4 t = boxes[b * OO + o];
    float area_b = (t.z - t.x) * (t.w - t.y);

    unsigned long long best = 0ULL;
    for (int p = p0 + threadIdx.x; p < p1; p += 256) {
        float4 pr = priors[p];
        float ax0 = pr.x - pr.z * 0.5f;
        float ay0 = pr.y - pr.w * 0.5f;
        float ax1 = pr.x + pr.z * 0.5f;
        float ay1 = pr.y + pr.w * 0.5f;
        float area_a = (ax1 - ax0) * (ay1 - ay0);
        float lx = fmaxf(ax0, t.x), ly = fmaxf(ay0, t.y);
        float rx = fminf(ax1, t.z), ry = fminf(ay1, t.w);
        float w = fmaxf(rx - lx, 0.0f), h = fmaxf(ry - ly, 0.0f);
        float inter = w * h;
        float iou = inter / (area_a + area_b - inter);
        unsigned long long key = ((unsigned long long)__float_as_uint(iou) << 32) |
                                 (unsigned long long)(0xFFFFFFFFu - (unsigned int)p);
        best = (key > best) ? key : best;
    }
    #pragma unroll
    for (int off = 32; off; off >>= 1) {
        unsigned long long other = __shfl_down(best, off, 64);
        best = (other > best) ? other : best;
    }
    __shared__ unsigned long long s_w[4];
    int wid = threadIdx.x >> 6;
    if ((threadIdx.x & 63) == 0) s_w[wid] = best;
    __syncthreads();
    if (threadIdx.x == 0) {
        unsigned long long m = s_w[0];
        for (int i = 1; i < 4; ++i) m = (s_w[i] > m) ? s_w[i] : m;
        atomicMax(&bp_key[b * OO + o], m);
    }
}

// Serial per batch: force each truth's best prior; later truths win on duplicates.
__global__ void k_scatter(const unsigned long long* __restrict__ bp_key,
                          float* __restrict__ bt_ov, int* __restrict__ bt_idx) {
    int b = blockIdx.x * blockDim.x + threadIdx.x;
    if (b < BB) {
        for (int o = 0; o < OO; ++o) {
            unsigned long long key = bp_key[b * OO + o];
            unsigned int p = 0xFFFFFFFFu - (unsigned int)(key & 0xFFFFFFFFull);
            bt_idx[b * PP + p] = o;
            bt_ov[b * PP + p] = 2.0f;
        }
    }
}

// Block = 64 contiguous rows (5184 floats, 16B-aligned). Fully-coalesced float4
// staging into LDS, then 16-lane log-softmax per row from LDS.
__global__ __launch_bounds__(256) void k_ce(const float4* __restrict__ conf4,
                                            const float4* __restrict__ loc4,
                                            const float4* __restrict__ priors,
                                            const float4* __restrict__ boxes,
                                            const int* __restrict__ labels,
                                            const float* __restrict__ bt_ov,
                                            const int* __restrict__ bt_idx,
                                            float* __restrict__ lc,
                                            int* __restrict__ num_pos,
                                            float* __restrict__ ls_slots,
                                            float* __restrict__ cs_slots) {
    __shared__ __align__(16) float s_conf[CHUNK];
    __shared__ int s_idx[ROWS];
    __shared__ float s_ov[ROWS];
    __shared__ float4 s_loc[ROWS];
    __shared__ float s_ce[ROWS];
    __shared__ float s_ls[ROWS];
    __shared__ int s_pos[ROWS];
    __shared__ float s_lc[ROWS];

    int r0 = blockIdx.x * ROWS;
    size_t base4 = (size_t)blockIdx.x * CHUNK4;

    #pragma unroll
    for (int it = 0; it < 6; ++it) {
        int idx = threadIdx.x + 256 * it;
        if (idx < CHUNK4) ((float4*)s_conf)[idx] = conf4[base4 + idx];
    }
    if (threadIdx.x < ROWS) {
        int r = r0 + threadIdx.x;
        s_idx[threadIdx.x] = bt_idx[r];
        s_ov[threadIdx.x] = bt_ov[r];
        s_loc[threadIdx.x] = loc4[r];
    }
    __syncthreads();

    int g = threadIdx.x >> 4;
    int lane = threadIdx.x & 15;
    int b0 = r0 / PP;

    for (int rl = g; rl < ROWS; rl += 16) {
        const float* row = s_conf + rl * CC;
        float x[6];
        #pragma unroll
        for (int s = 0; s < 6; ++s) {
            int idx = lane + 16 * s;
            x[s] = (idx < CC) ? row[idx] : -INFINITY;
        }

        float m = fmaxf(fmaxf(fmaxf(x[0], x[1]), fmaxf(x[2], x[3])), fmaxf(x[4], x[5]));
        #pragma unroll
        for (int off = 1; off < 16; off <<= 1) m = fmaxf(m, __shfl_xor(m, off, 16));

        float sum = 0.0f;
        #pragma unroll
        for (int s = 0; s < 6; ++s) sum += __expf(x[s] - m);
        #pragma unroll
        for (int off = 1; off < 16; off <<= 1) sum += __shfl_xor(sum, off, 16);
        float lse = __logf(sum) + m;

        int r = r0 + rl;
        int b = b0 + (r >= (b0 + 1) * PP ? 1 : 0);
        int p = r - b * PP;
        int t = s_idx[rl];
        float ov = s_ov[rl];
        int cls = labels[b * OO + t];  // broadcast load (all lanes same addr)
        if (ov < 0.5f) cls = 0;

        // fetch x[cls] without dynamic register indexing
        int slot = cls >> 4;
        float xs = x[0];
        #pragma unroll
        for (int s = 1; s < 6; ++s) xs = (slot == s) ? x[s] : xs;
        float xt = __shfl(xs, cls & 15, 16);
        float ce = lse - xt;

        if (lane == 0) {
            bool pos = cls > 0;
            s_lc[rl] = pos ? 0.0f : ce;
            float s = 0.0f;
            if (pos) {
                float4 tb = boxes[b * OO + t];  // corner form
                float4 pr = priors[p];          // center form
                float gx = ((tb.x + tb.z) * 0.5f - pr.x) / (V0c * pr.z);
                float gy = ((tb.y + tb.w) * 0.5f - pr.y) / (V0c * pr.w);
                float gw = logf((tb.z - tb.x) / pr.z) / V1c;
                float gh = logf((tb.w - tb.y) / pr.w) / V1c;
                float4 lp = s_loc[rl];
                float d0 = fabsf(lp.x - gx);
                float d1 = fabsf(lp.y - gy);
                float d2 = fabsf(lp.z - gw);
                float d3 = fabsf(lp.w - gh);
                s += (d0 < 1.0f) ? 0.5f * d0 * d0 : d0 - 0.5f;
                s += (d1 < 1.0f) ? 0.5f * d1 * d1 : d1 - 0.5f;
                s += (d2 < 1.0f) ? 0.5f * d2 * d2 : d2 - 0.5f;
                s += (d3 < 1.0f) ? 0.5f * d3 * d3 : d3 - 0.5f;
            }
            s_ce[rl] = pos ? ce : 0.0f;
            s_ls[rl] = s;
            s_pos[rl] = pos ? 1 : 0;
        }
    }
    __syncthreads();

    if (threadIdx.x < ROWS) {
        lc[r0 + threadIdx.x] = s_lc[threadIdx.x];  // coalesced
    }
    if (threadIdx.x == 0) {
        float ces = 0.0f, lss = 0.0f;
        int c0 = 0, c1 = 0;
        int split = (b0 + 1) * PP;  // rows >= split belong to b0+1
        for (int i = 0; i < ROWS; ++i) {
            ces += s_ce[i];
            lss += s_ls[i];
            if (r0 + i < split) c0 += s_pos[i]; else c1 += s_pos[i];
        }
        if (c0) atomicAdd(&num_pos[b0], c0);
        if (c1) atomicAdd(&num_pos[b0 + 1], c1);
        if (c0 + c1) {
            int sl = blockIdx.x & 63;
            atomicAdd(&ls_slots[sl], lss);
            atomicAdd(&cs_slots[sl], ces);
        }
    }
}

// One block per batch: exact top-k sum of lc via 31-bit MSB radix select.
__global__ __launch_bounds__(1024) void k_select(const float* __restrict__ lc,
                                                 const int* __restrict__ num_pos,
                                                 float* __restrict__ cs_slots) {
    int b = blockIdx.x;
    const float* v = lc + (size_t)b * PP;
    int np = num_pos[b];
    long long k0 = 3LL * (long long)np;
    int k = (k0 < (long long)(PP - 1)) ? (int)k0 : (PP - 1);

    __shared__ int s_cnt[16];
    __shared__ float s_sum[16];
    __shared__ unsigned int s_prefix;
    __shared__ int s_k;

    unsigned int val[24];
    #pragma unroll
    for (int i = 0; i < 24; ++i) {
        int idx = threadIdx.x + i * 1024;
        val[i] = (idx < PP) ? __float_as_uint(v[idx]) : 0u;
    }

    if (k <= 0) return;  // uniform per block

    if (threadIdx.x == 0) { s_prefix = 0u; s_k = k; }
    __syncthreads();

    unsigned int prefix = 0u;
    for (int bit = 30; bit >= 0; --bit) {
        unsigned int cand = prefix | (1u << bit);
        unsigned int hi = cand >> bit;
        int c = 0;
        #pragma unroll
        for (int i = 0; i < 24; ++i) c += ((val[i] >> bit) == hi);
        #pragma unroll
        for (int off = 32; off; off >>= 1) c += __shfl_down(c, off, 64);
        int wid = threadIdx.x >> 6;
        if ((threadIdx.x & 63) == 0) s_cnt[wid] = c;
        __syncthreads();
        if (threadIdx.x == 0) {
            int tot = 0;
            #pragma unroll
            for (int i = 0; i < 16; ++i) tot += s_cnt[i];
            if (tot >= s_k) s_prefix = cand; else s_k -= tot;
        }
        __syncthreads();
        prefix = s_prefix;
    }

    float fv = __uint_as_float(prefix);
    float ssum = 0.0f;
    int cgt = 0;
    #pragma unroll
    for (int i = 0; i < 24; ++i) {
        if (val[i] > prefix) { ssum += __uint_as_float(val[i]); cgt++; }
    }
    #pragma unroll
    for (int off = 32; off; off >>= 1) {
        ssum += __shfl_down(ssum, off, 64);
        cgt += __shfl_down(cgt, off, 64);
    }
    int wid = threadIdx.x >> 6;
    if ((threadIdx.x & 63) == 0) { s_cnt[wid] = cgt; s_sum[wid] = ssum; }
    __syncthreads();
    if (threadIdx.x == 0) {
        int ct = 0;
        float st = 0.0f;
        #pragma unroll
        for (int i = 0; i < 16; ++i) { ct += s_cnt[i]; st += s_sum[i]; }
        float topk = st + (float)(k - ct) * fv;
        atomicAdd(&cs_slots[b], topk);  // b < 32: spread, 1 atomic/block
    }
}

__global__ void k_final(const int* __restrict__ num_pos,
                        const float* __restrict__ ls_slots,
                        const float* __restrict__ cs_slots,
                        float* __restrict__ out) {
    if (threadIdx.x == 0 && blockIdx.x == 0) {
        int N = 0;
        for (int b = 0; b < BB; ++b) N += num_pos[b];
        float Sl = 0.0f, Sc = 0.0f;
        for (int i = 0; i < 64; ++i) { Sl += ls_slots[i]; Sc += cs_slots[i]; }
        float fN = (float)N;
        out[0] = Sl / fN + Sc / fN;
    }
}

extern "C" void kernel_launch(void* const* d_in, const int* in_sizes, int n_in,
                              void* d_out, int out_size, void* d_ws, size_t ws_size,
                              hipStream_t stream) {
    const float* loc_preds = (const float*)d_in[0];   // [B,P,4]
    const float* conf_preds = (const float*)d_in[1];  // [B,P,C]
    const float* priors = (const float*)d_in[2];      // [P,4] center form
    const float* boxes = (const float*)d_in[3];       // [B,O,4] corner form
    const int* labels = (const int*)d_in[4];          // [B,O]

    char* ws = (char*)d_ws;
    const size_t SZ_BP = (size_t)BB * PP;
    int* bt_idx = (int*)(ws);
    float* bt_ov = (float*)(ws + SZ_BP * 4);
    float* lc = (float*)(ws + SZ_BP * 8);
    unsigned long long* bp_key = (unsigned long long*)(ws + SZ_BP * 12);
    float* ls_slots = (float*)(ws + SZ_BP * 12 + (size_t)BB * OO * 8);
    float* cs_slots = ls_slots + 64;
    int* num_pos = (int*)(cs_slots + 64);

    k_init<<<4, 256, 0, stream>>>(bp_key, ls_slots, cs_slots, num_pos);

    dim3 g1((PP + 255) / 256, BB);
    k_match<<<g1, 256, 0, stream>>>((const float4*)priors, (const float4*)boxes,
                                    bt_ov, bt_idx);

    dim3 g2(OO, BB, 8);
    k_bestprior<<<g2, 256, 0, stream>>>((const float4*)priors, (const float4*)boxes,
                                        bp_key);

    k_scatter<<<1, 64, 0, stream>>>(bp_key, bt_ov, bt_idx);

    int rows = BB * PP;
    k_ce<<<rows / ROWS, 256, 0, stream>>>((const float4*)conf_preds,
                                          (const float4*)loc_preds,
                                          (const float4*)priors, (const float4*)boxes,
                                          labels, bt_ov, bt_idx, lc, num_pos,
                                          ls_slots, cs_slots);

    k_select<<<BB, 1024, 0, stream>>>(lc, num_pos, cs_slots);

    k_final<<<1, 64, 0, stream>>>(num_pos, ls_slots, cs_slots, (float*)d_out);
}